// Round 16
// baseline (1044.204 us; speedup 1.0000x reference)
//
#include <hip/hip_runtime.h>
#include <hip/hip_cooperative_groups.h>
#include <math.h>

namespace cg = cooperative_groups;

#define NND 50000
#define NED 800000
#define ETOT 850000   // edges + self-loops
#define NG 256
#define FEAT 128
#define CCH 256       // HEADS*HID
#define OUTD 128
#define NEG 0.2f
#define NBLK 196      // ceil(NND/256)
#define M2 50048      // NND padded to 128
#define CGRID 1024    // coop grid: 4 blocks/CU, safely co-resident (8 VGPR, 1KB LDS)

typedef __attribute__((ext_vector_type(8))) _Float16 half8;
typedef __attribute__((ext_vector_type(4))) _Float16 half4;
typedef __attribute__((ext_vector_type(4))) float floatx4;

#if __has_builtin(__builtin_amdgcn_global_load_lds)
#define GLOAD16(g, l) __builtin_amdgcn_global_load_lds( \
    (const __attribute__((address_space(1))) void*)(g), \
    (__attribute__((address_space(3))) void*)(l), 16, 0, 0)
#define HAVE_GLDS 1
#else
#define HAVE_GLDS 0
#endif

// ---------------- fused prep + CSR build (single cooperative kernel) ----------------
// phase 0: zero deg | graph bounds | x->fp16 | W->fp16^T   (all independent)
// phase 1: degree count (atomics)       phase 2: per-block sums (blocks<196)
// phase 3: scan block sums (block 0)    phase 4: rowptr/cursor write
// phase 5: scatter
// 1024 blocks: edge phases get 262k threads (~3.2 edges/thread) — R15's 196-block
// version serialized 17 atomics/thread and ran 177us; this restores parallelism.

__global__ __launch_bounds__(256) void csr_coop_kernel(const int* __restrict__ ei,
                                                       const int* __restrict__ batch,
                                                       const float4* __restrict__ x,
                                                       const float* __restrict__ W0,
                                                       const float* __restrict__ W1,
                                                       const float* __restrict__ W2,
                                                       int* __restrict__ deg,
                                                       int* __restrict__ rowptr,
                                                       int* __restrict__ cursor,
                                                       int* __restrict__ csrsrc,
                                                       int* __restrict__ bsum,
                                                       int* __restrict__ boff,
                                                       int* __restrict__ total,
                                                       int* __restrict__ gstart,
                                                       half4* __restrict__ xo,
                                                       _Float16* __restrict__ wt0,
                                                       _Float16* __restrict__ wt1,
                                                       _Float16* __restrict__ wt2) {
    cg::grid_group grid = cg::this_grid();
    __shared__ int tile[256];
    const int t = threadIdx.x;
    const int b = blockIdx.x;
    const int gid = b * 256 + t;
    const int gsz = CGRID * 256;

    // ---- phase 0: zero deg | bounds | decomp_x | wdecomp ----
    for (int i = gid; i < NND + 1; i += gsz) deg[i] = 0;
    for (int i = gid; i < NND; i += gsz) {
        int bb = batch[i];
        int bp = (i == 0) ? -1 : batch[i - 1];
        for (int g = bp + 1; g <= bb; ++g) gstart[g] = i;
        if (i == NND - 1)
            for (int g = bb + 1; g <= NG; ++g) gstart[g] = NND;
    }
    for (int i = gid; i < NND * FEAT / 4; i += gsz) {
        float4 v = x[i];
        half4 o;
        o[0] = (_Float16)v.x; o[1] = (_Float16)v.y;
        o[2] = (_Float16)v.z; o[3] = (_Float16)v.w;
        xo[i] = o;
    }
    for (int j = gid; j < 256 * 128; j += gsz) {
        int n = j >> 7, k = j & 127;
        wt0[j] = (_Float16)W0[k * 256 + n];
    }
    for (int j = gid; j < 256 * 256; j += gsz) {
        int n = j >> 8, k = j & 255;
        wt1[j] = (_Float16)W1[k * 256 + n];
        int n2 = j >> 8, k2 = j & 255;
        wt2[j] = (_Float16)W2[k2 * 256 + n2];
    }
    grid.sync();

    // ---- phase 1: degree count ----
    for (int e = gid; e < ETOT; e += gsz) {
        int dst = (e < NED) ? ei[NED + e] : (e - NED);
        atomicAdd(&deg[dst], 1);
    }
    grid.sync();

    // ---- phase 2: per-block sums (blocks < NBLK) ----
    if (b < NBLK) {
        int i = b * 256 + t;
        tile[t] = (i < NND) ? deg[i] : 0;
        __syncthreads();
        for (int s = 128; s > 0; s >>= 1) {
            if (t < s) tile[t] += tile[t + s];
            __syncthreads();
        }
        if (t == 0) bsum[b] = tile[0];
    }
    grid.sync();

    // ---- phase 3: exclusive scan of block sums (block 0) ----
    if (b == 0) {
        int v = (t < NBLK) ? bsum[t] : 0;
        __syncthreads();
        tile[t] = v;
        __syncthreads();
        for (int off = 1; off < 256; off <<= 1) {
            int u = (t >= off) ? tile[t - off] : 0;
            __syncthreads();
            tile[t] += u;
            __syncthreads();
        }
        if (t < NBLK) boff[t] = tile[t] - v;
        if (t == 255) *total = tile[255];
    }
    grid.sync();

    // ---- phase 4: local scan + offset -> rowptr, cursor ----
    if (b < NBLK) {
        int i = b * 256 + t;
        int v = (i < NND) ? deg[i] : 0;
        __syncthreads();
        tile[t] = v;
        __syncthreads();
        for (int off = 1; off < 256; off <<= 1) {
            int u = (t >= off) ? tile[t - off] : 0;
            __syncthreads();
            tile[t] += u;
            __syncthreads();
        }
        if (i < NND) {
            int r = boff[b] + tile[t] - v;
            rowptr[i] = r;
            cursor[i] = r;
        }
        if (i == 0) rowptr[NND] = *total;
    }
    grid.sync();

    // ---- phase 5: scatter ----
    for (int e = gid; e < ETOT; e += gsz) {
        int s, d;
        if (e < NED) { s = ei[e]; d = ei[NED + e]; } else { s = d = e - NED; }
        int pos = atomicAdd(&cursor[d], 1);
        csrsrc[pos] = s;
    }
}

// ---------------- MFMA GEMM + fused alpha epilogue (R10/R14 structure) ----------------
// H[M2,256] = A[M2,K] @ Wt[256,K]^T  (fp16 in, f32 acc, fp16 out)
// BOTH A and B staged via global_load_lds, XOR-swizzled; direct C stores.

#define BK 64

__global__ __launch_bounds__(256, 3) void gemm_mfma_kernel(
        const _Float16* __restrict__ A,
        const _Float16* __restrict__ Bt,
        const float* __restrict__ as_, const float* __restrict__ ad_,
        _Float16* __restrict__ Hm,
        float* __restrict__ asrc, float* __restrict__ adst, int K) {
    __shared__ _Float16 AsF[128 * 64];
    __shared__ _Float16 BsF[128 * 64];
    const int t = threadIdx.x;
    const int bn = blockIdx.x * 128;
    const int bm = blockIdx.y * 128;
    const int lane = t & 63, wv = t >> 6;
    const int wm = (wv >> 1) * 64, wn = (wv & 1) * 64;
    const int fr = lane & 15, q = lane >> 4;

    floatx4 acc[4][4] = {};

    const int lrow = t >> 3;          // 0..31
    const int c8 = t & 7;             // 16B block slot within LDS row

    for (int k0 = 0; k0 < K; k0 += BK) {
        for (int p = 0; p < 4; p++) {
            int row = p * 32 + lrow;
            int g8 = c8 ^ (row & 7);  // swizzled global block
            const _Float16* ga = A + (size_t)(bm + row) * K + k0 + g8 * 8;
            const _Float16* gb = Bt + (size_t)(bn + row) * K + k0 + g8 * 8;
#if HAVE_GLDS
            GLOAD16(ga, &AsF[row * 64 + c8 * 8]);
            GLOAD16(gb, &BsF[row * 64 + c8 * 8]);
#else
            *(half8*)&AsF[row * 64 + c8 * 8] = *(const half8*)ga;
            *(half8*)&BsF[row * 64 + c8 * 8] = *(const half8*)gb;
#endif
        }
        __syncthreads();
        for (int kc = 0; kc < 2; kc++) {
            half8 af[4], bf[4];
            int kb = kc * 4 + q;      // 16B k-block of this quad's fragment
            int cs = (kb ^ (fr & 7)) * 8;
            for (int mi = 0; mi < 4; mi++)
                af[mi] = *(const half8*)&AsF[(wm + mi * 16 + fr) * 64 + cs];
            for (int ni = 0; ni < 4; ni++)
                bf[ni] = *(const half8*)&BsF[(wn + ni * 16 + fr) * 64 + cs];
            for (int mi = 0; mi < 4; mi++)
                for (int ni = 0; ni < 4; ni++)
                    acc[mi][ni] = __builtin_amdgcn_mfma_f32_16x16x32_f16(
                        af[mi], bf[ni], acc[mi][ni], 0, 0, 0);
        }
        __syncthreads();
    }

    // C/D layout: col = lane&15 (fr), row = q*4 + reg
    for (int mi = 0; mi < 4; mi++) {
        int row0 = bm + wm + mi * 16 + q * 4;
        for (int ni = 0; ni < 4; ni++) {
            int col = bn + wn + ni * 16 + fr;
            for (int r = 0; r < 4; r++)
                Hm[(size_t)(row0 + r) * CCH + col] = (_Float16)acc[mi][ni][r];
        }
    }

    // fused alpha: this wave's head
    const int hd = (bn + wn) >> 6;
    float asf[4], adf[4];
    for (int ni = 0; ni < 4; ni++) {
        asf[ni] = as_[hd * 64 + ni * 16 + fr];
        adf[ni] = ad_[hd * 64 + ni * 16 + fr];
    }
    for (int mi = 0; mi < 4; mi++)
        for (int r = 0; r < 4; r++) {
            float ps = 0.f, pd = 0.f;
            for (int ni = 0; ni < 4; ni++) {
                float v = acc[mi][ni][r];
                ps += v * asf[ni];
                pd += v * adf[ni];
            }
            for (int m = 1; m < 16; m <<= 1) {
                ps += __shfl_xor(ps, m, 64);
                pd += __shfl_xor(pd, m, 64);
            }
            if (fr == 0) {
                int row = bm + wm + mi * 16 + q * 4 + r;
                asrc[row * 4 + hd] = ps;
                adst[row * 4 + hd] = pd;
            }
        }
}

// ---------------- fused softmax + weighted fp16 gather + bias + ELU -> fp16 ----------------
// One wave per dst node; software-pipelined 16-edge chunks (R11/R13/R14).

__global__ __launch_bounds__(256) void agg_kernel(const _Float16* __restrict__ H16,
                                                  const float* __restrict__ asrc,
                                                  const float* __restrict__ adst,
                                                  const int* __restrict__ rowptr,
                                                  const int* __restrict__ csrsrc,
                                                  const float4* __restrict__ bias4,
                                                  half8* __restrict__ xo) {
    int wave = threadIdx.x >> 6, lane = threadIdx.x & 63;
    int n = blockIdx.x * 4 + wave;
    if (n >= NND) return;
    int rs = rowptr[n], re = rowptr[n + 1];
    int hd = lane >> 4;          // head for exp computation
    int sub = lane & 15;
    int l32 = lane & 31;         // output channel-group (8 ch)
    int myh = l32 >> 3;          // head of my output channels
    int epar = lane >> 5;        // edge parity this half handles
    float adv = adst[n * 4 + hd];
    float acc[8] = {};
    float ssum = 0.f;
    const _Float16* hb = H16 + l32 * 8;

    // prologue prefetch
    int sl = rs + sub;
    bool ok = sl < re;
    int idx = ok ? csrsrc[sl] : 0;
    float aval = asrc[idx * 4 + hd];

    for (int e0 = rs; e0 < re; e0 += 16) {
        float ev = 0.f;
        if (ok) {
            float a = aval + adv;
            a = a > 0.f ? a : NEG * a;
            ev = __expf(a);
        }
        ssum += ev;
        int idxv = idx;
        // prefetch next chunk (loads issue before the gather phase below)
        int sl2 = e0 + 16 + sub;
        bool ok2 = sl2 < re;
        int idx2 = ok2 ? csrsrc[sl2] : 0;
        float aval2 = asrc[idx2 * 4 + hd];
        int cnt = re - e0; if (cnt > 16) cnt = 16;
        #pragma unroll
        for (int j2 = 0; j2 < 8; j2++) {
            if (j2 * 2 >= cnt) break;
            int j = j2 * 2 + epar;
            int s = __shfl(idxv, j, 64);
            float ww = __shfl(ev, myh * 16 + j, 64);
            half8 hv = *(const half8*)&hb[(size_t)s * CCH];
            #pragma unroll
            for (int k = 0; k < 8; k++) acc[k] += ww * (float)hv[k];
        }
        idx = idx2; aval = aval2; ok = ok2;
    }
    // per-head softmax denominator: reduce over the 16 sub-lanes of each quarter
    for (int off = 1; off < 16; off <<= 1) ssum += __shfl_xor(ssum, off, 64);
    float inv = 1.f / __shfl(ssum, myh * 16, 64);
    // fold the two edge-parity halves
    #pragma unroll
    for (int k = 0; k < 8; k++) acc[k] += __shfl_xor(acc[k], 32, 64);
    if (lane < 32) {
        float4 b0 = bias4[l32 * 2], b1 = bias4[l32 * 2 + 1];
        float o[8];
        o[0] = acc[0] * inv + b0.x; o[1] = acc[1] * inv + b0.y;
        o[2] = acc[2] * inv + b0.z; o[3] = acc[3] * inv + b0.w;
        o[4] = acc[4] * inv + b1.x; o[5] = acc[5] * inv + b1.y;
        o[6] = acc[6] * inv + b1.z; o[7] = acc[7] * inv + b1.w;
        half8 h;
        #pragma unroll
        for (int k = 0; k < 8; k++) {
            float v = o[k];
            v = v > 0.f ? v : expm1f(v);
            h[k] = (_Float16)v;
        }
        xo[(size_t)n * 32 + l32] = h;
    }
}

// ---------------- pooling + final linear + L2 norm (fused) ----------------

__global__ __launch_bounds__(256) void poolfinal_kernel(const _Float16* __restrict__ xa,
                                                        const int* __restrict__ gstart,
                                                        const float* __restrict__ Wf,
                                                        const float* __restrict__ bfv,
                                                        float* __restrict__ out) {
    int g = blockIdx.x, t = threadIdx.x;
    __shared__ float gm[256];
    __shared__ float red[128];
    int s = gstart[g], e = gstart[g + 1];
    float acc = 0.f;
    for (int i = s; i < e; i++)
        acc += (float)xa[(size_t)i * CCH + t];
    int cnt = e - s;
    gm[t] = acc / (float)(cnt > 0 ? cnt : 1);
    __syncthreads();
    float a = 0.f;
    if (t < OUTD) {
        a = bfv[t];
        for (int k = 0; k < CCH; k++) a += gm[k] * Wf[k * OUTD + t];
        red[t] = a * a;
    }
    __syncthreads();
    for (int sft = 64; sft > 0; sft >>= 1) {
        if (t < sft) red[t] += red[t + sft];
        __syncthreads();
    }
    if (t < OUTD) out[g * OUTD + t] = a / fmaxf(sqrtf(red[0]), 1e-12f);
}

// ---------------- launch ----------------

extern "C" void kernel_launch(void* const* d_in, const int* in_sizes, int n_in,
                              void* d_out, int out_size, void* d_ws, size_t ws_size,
                              hipStream_t stream) {
    const float* x     = (const float*)d_in[0];
    const int*   ei    = (const int*)d_in[1];
    const int*   batch = (const int*)d_in[2];
    const float* W[3]  = {(const float*)d_in[3], (const float*)d_in[7],  (const float*)d_in[11]};
    const float* As[3] = {(const float*)d_in[4], (const float*)d_in[8],  (const float*)d_in[12]};
    const float* Ad[3] = {(const float*)d_in[5], (const float*)d_in[9],  (const float*)d_in[13]};
    const float* Bb[3] = {(const float*)d_in[6], (const float*)d_in[10], (const float*)d_in[14]};
    const float* Wf    = (const float*)d_in[15];
    const float* bf    = (const float*)d_in[16];
    float* out = (float*)d_out;

    // workspace layout
    _Float16* H16   = (_Float16*)d_ws;                            // M2*256 fp16 (gemm out / gather in)
    _Float16* act16 = H16 + (size_t)M2 * CCH;                     // M2*256 fp16 (agg out / gemm in)
    _Float16* wt0   = act16 + (size_t)M2 * CCH;                   // 256*128
    _Float16* wt1   = wt0 + 256 * 128;                            // 256*256
    _Float16* wt2   = wt1 + 256 * 256;                            // 256*256
    float* asrc  = (float*)(wt2 + 256 * 256);                     // M2*4
    float* adst  = asrc + (size_t)M2 * 4;                         // M2*4
    int* deg     = (int*)(adst + (size_t)M2 * 4);                 // NND+1
    int* rowptr  = deg + (NND + 1);
    int* cursor  = rowptr + (NND + 1);
    int* csrsrc  = cursor + (NND + 1);                            // ETOT
    int* gstart  = csrsrc + ETOT;                                 // NG+1
    int* bsum    = gstart + (NG + 1);                             // NBLK
    int* boff    = bsum + NBLK;
    int* total   = boff + NBLK;

    _Float16* wt[3] = {wt0, wt1, wt2};

    // fused prep + CSR build: one cooperative dispatch
    {
        const float4* x4 = (const float4*)x;
        half4* xo = (half4*)act16;
        void* args[] = {(void*)&ei, (void*)&batch, (void*)&x4,
                        (void*)&W[0], (void*)&W[1], (void*)&W[2],
                        (void*)&deg, (void*)&rowptr, (void*)&cursor, (void*)&csrsrc,
                        (void*)&bsum, (void*)&boff, (void*)&total, (void*)&gstart,
                        (void*)&xo, (void*)&wt0, (void*)&wt1, (void*)&wt2};
        hipLaunchCooperativeKernel((void*)csr_coop_kernel, dim3(CGRID), dim3(256),
                                   args, 0, stream);
    }

    // 3 GAT layers
    int K = FEAT;
    for (int l = 0; l < 3; l++) {
        dim3 g(2, M2 / 128);
        gemm_mfma_kernel<<<g, 256, 0, stream>>>(act16, wt[l], As[l], Ad[l], H16, asrc, adst, K);
        agg_kernel<<<(NND + 3) / 4, 256, 0, stream>>>(H16, asrc, adst, rowptr, csrsrc,
                                                      (const float4*)Bb[l], (half8*)act16);
        K = CCH;
    }

    // global mean pool + final linear + L2 normalize (fused)
    poolfinal_kernel<<<NG, 256, 0, stream>>>(act16, gstart, Wf, bf, out);
}

// Round 17
// 512.810 us; speedup vs baseline: 2.0362x; 2.0362x over previous
//
#include <hip/hip_runtime.h>
#include <math.h>

#define NND 50000
#define NED 800000
#define ETOT 850000   // edges + self-loops
#define NG 256
#define FEAT 128
#define CCH 256       // HEADS*HID
#define OUTD 128
#define NEG 0.2f
#define NBLK 196      // ceil(NND/256)
#define M2 50048      // NND padded to 128
#define XBLK 6250     // ceil(NND*FEAT/4 / 256)

typedef __attribute__((ext_vector_type(8))) _Float16 half8;
typedef __attribute__((ext_vector_type(4))) _Float16 half4;
typedef __attribute__((ext_vector_type(4))) float floatx4;

#if __has_builtin(__builtin_amdgcn_global_load_lds)
#define GLOAD16(g, l) __builtin_amdgcn_global_load_lds( \
    (const __attribute__((address_space(1))) void*)(g), \
    (__attribute__((address_space(3))) void*)(l), 16, 0, 0)
#define HAVE_GLDS 1
#else
#define HAVE_GLDS 0
#endif

// ---------------- CSR build ----------------

__global__ void count_kernel(const int* __restrict__ ei, int* __restrict__ deg) {
    int e = blockIdx.x * 256 + threadIdx.x;
    if (e >= ETOT) return;
    int dst = (e < NED) ? ei[NED + e] : (e - NED);
    atomicAdd(&deg[dst], 1);
}

__global__ __launch_bounds__(256) void scan_part_kernel(const int* __restrict__ deg,
                                                        int* __restrict__ bsum) {
    __shared__ int tile[256];
    int i = blockIdx.x * 256 + threadIdx.x;
    tile[threadIdx.x] = (i < NND) ? deg[i] : 0;
    __syncthreads();
    for (int s = 128; s > 0; s >>= 1) {
        if (threadIdx.x < s) tile[threadIdx.x] += tile[threadIdx.x + s];
        __syncthreads();
    }
    if (threadIdx.x == 0) bsum[blockIdx.x] = tile[0];
}

// merged: every block redundantly scans the 196 block sums in LDS (cheap),
// then does its local scan — removes the separate single-block scan_bsum
// dispatch and the boff/total round-trip (coop grid.sync measured 25-100us
// per sync on gfx950 — R15/R16 — so fusion must be sync-free).
__global__ __launch_bounds__(256) void scan_write_kernel(const int* __restrict__ deg,
                                                         const int* __restrict__ bsum,
                                                         int* __restrict__ rowptr,
                                                         int* __restrict__ cursor) {
    __shared__ int bs[256];
    __shared__ int tile[256];
    const int t = threadIdx.x, b = blockIdx.x;
    // inclusive scan of bsum (all blocks do this redundantly)
    bs[t] = (t < NBLK) ? bsum[t] : 0;
    __syncthreads();
    for (int off = 1; off < 256; off <<= 1) {
        int u = (t >= off) ? bs[t - off] : 0;
        __syncthreads();
        bs[t] += u;
        __syncthreads();
    }
    int boffb = (b == 0) ? 0 : bs[b - 1];
    int total = bs[NBLK - 1];
    // local scan of this block's 256 degrees
    int i = b * 256 + t;
    int v = (i < NND) ? deg[i] : 0;
    tile[t] = v;
    __syncthreads();
    for (int off = 1; off < 256; off <<= 1) {
        int u = (t >= off) ? tile[t - off] : 0;
        __syncthreads();
        tile[t] += u;
        __syncthreads();
    }
    if (i < NND) {
        int r = boffb + tile[t] - v;
        rowptr[i] = r;
        cursor[i] = r;
    }
    if (i == 0) rowptr[NND] = total;
}

__global__ void scatter_kernel(const int* __restrict__ ei, int* __restrict__ cursor,
                               int* __restrict__ csrsrc) {
    int e = blockIdx.x * 256 + threadIdx.x;
    if (e >= ETOT) return;
    int s, d;
    if (e < NED) { s = ei[e]; d = ei[NED + e]; } else { s = d = e - NED; }
    int pos = atomicAdd(&cursor[d], 1);
    csrsrc[pos] = s;
}

// ---------------- fused prep: zero deg | graph bounds | x->fp16 | W->fp16^T ----------------

__global__ __launch_bounds__(256) void prep_kernel(const int* __restrict__ batch,
                                                   int* __restrict__ deg,
                                                   int* __restrict__ gstart,
                                                   const float4* __restrict__ x,
                                                   half4* __restrict__ xo,
                                                   const float* __restrict__ W0,
                                                   const float* __restrict__ W1,
                                                   const float* __restrict__ W2,
                                                   _Float16* __restrict__ wt0,
                                                   _Float16* __restrict__ wt1,
                                                   _Float16* __restrict__ wt2) {
    int b = blockIdx.x;
    if (b < 196) {
        int i = b * 256 + threadIdx.x;
        if (i < NND + 1) deg[i] = 0;
        return;
    }
    b -= 196;
    if (b < 196) {
        int i = b * 256 + threadIdx.x;
        if (i >= NND) return;
        int bb = batch[i];
        int bp = (i == 0) ? -1 : batch[i - 1];
        for (int g = bp + 1; g <= bb; ++g) gstart[g] = i;
        if (i == NND - 1)
            for (int g = bb + 1; g <= NG; ++g) gstart[g] = NND;
        return;
    }
    b -= 196;
    if (b < XBLK) {
        int i = b * 256 + threadIdx.x;
        if (i >= NND * FEAT / 4) return;
        float4 v = x[i];
        half4 o;
        o[0] = (_Float16)v.x; o[1] = (_Float16)v.y;
        o[2] = (_Float16)v.z; o[3] = (_Float16)v.w;
        xo[i] = o;
        return;
    }
    b -= XBLK;
    int j = b * 256 + threadIdx.x;
    if (j < 256 * 128) {
        int n = j >> 7, k = j & 127;
        wt0[j] = (_Float16)W0[k * 256 + n];
        return;
    }
    j -= 256 * 128;
    if (j < 256 * 256) {
        int n = j >> 8, k = j & 255;
        wt1[j] = (_Float16)W1[k * 256 + n];
        return;
    }
    j -= 256 * 256;
    if (j < 256 * 256) {
        int n = j >> 8, k = j & 255;
        wt2[j] = (_Float16)W2[k * 256 + n];
    }
}

// ---------------- MFMA GEMM + fused alpha epilogue (R10/R14 structure) ----------------
// H[M2,256] = A[M2,K] @ Wt[256,K]^T  (fp16 in, f32 acc, fp16 out)
// BOTH A and B staged via global_load_lds, XOR-swizzled; direct C stores.

#define BK 64

__global__ __launch_bounds__(256, 3) void gemm_mfma_kernel(
        const _Float16* __restrict__ A,
        const _Float16* __restrict__ Bt,
        const float* __restrict__ as_, const float* __restrict__ ad_,
        _Float16* __restrict__ Hm,
        float* __restrict__ asrc, float* __restrict__ adst, int K) {
    __shared__ _Float16 AsF[128 * 64];
    __shared__ _Float16 BsF[128 * 64];
    const int t = threadIdx.x;
    const int bn = blockIdx.x * 128;
    const int bm = blockIdx.y * 128;
    const int lane = t & 63, wv = t >> 6;
    const int wm = (wv >> 1) * 64, wn = (wv & 1) * 64;
    const int fr = lane & 15, q = lane >> 4;

    floatx4 acc[4][4] = {};

    const int lrow = t >> 3;          // 0..31
    const int c8 = t & 7;             // 16B block slot within LDS row

    for (int k0 = 0; k0 < K; k0 += BK) {
        for (int p = 0; p < 4; p++) {
            int row = p * 32 + lrow;
            int g8 = c8 ^ (row & 7);  // swizzled global block
            const _Float16* ga = A + (size_t)(bm + row) * K + k0 + g8 * 8;
            const _Float16* gb = Bt + (size_t)(bn + row) * K + k0 + g8 * 8;
#if HAVE_GLDS
            GLOAD16(ga, &AsF[row * 64 + c8 * 8]);
            GLOAD16(gb, &BsF[row * 64 + c8 * 8]);
#else
            *(half8*)&AsF[row * 64 + c8 * 8] = *(const half8*)ga;
            *(half8*)&BsF[row * 64 + c8 * 8] = *(const half8*)gb;
#endif
        }
        __syncthreads();
        for (int kc = 0; kc < 2; kc++) {
            half8 af[4], bf[4];
            int kb = kc * 4 + q;      // 16B k-block of this quad's fragment
            int cs = (kb ^ (fr & 7)) * 8;
            for (int mi = 0; mi < 4; mi++)
                af[mi] = *(const half8*)&AsF[(wm + mi * 16 + fr) * 64 + cs];
            for (int ni = 0; ni < 4; ni++)
                bf[ni] = *(const half8*)&BsF[(wn + ni * 16 + fr) * 64 + cs];
            for (int mi = 0; mi < 4; mi++)
                for (int ni = 0; ni < 4; ni++)
                    acc[mi][ni] = __builtin_amdgcn_mfma_f32_16x16x32_f16(
                        af[mi], bf[ni], acc[mi][ni], 0, 0, 0);
        }
        __syncthreads();
    }

    // C/D layout: col = lane&15 (fr), row = q*4 + reg
    for (int mi = 0; mi < 4; mi++) {
        int row0 = bm + wm + mi * 16 + q * 4;
        for (int ni = 0; ni < 4; ni++) {
            int col = bn + wn + ni * 16 + fr;
            for (int r = 0; r < 4; r++)
                Hm[(size_t)(row0 + r) * CCH + col] = (_Float16)acc[mi][ni][r];
        }
    }

    // fused alpha: this wave's head
    const int hd = (bn + wn) >> 6;
    float asf[4], adf[4];
    for (int ni = 0; ni < 4; ni++) {
        asf[ni] = as_[hd * 64 + ni * 16 + fr];
        adf[ni] = ad_[hd * 64 + ni * 16 + fr];
    }
    for (int mi = 0; mi < 4; mi++)
        for (int r = 0; r < 4; r++) {
            float ps = 0.f, pd = 0.f;
            for (int ni = 0; ni < 4; ni++) {
                float v = acc[mi][ni][r];
                ps += v * asf[ni];
                pd += v * adf[ni];
            }
            for (int m = 1; m < 16; m <<= 1) {
                ps += __shfl_xor(ps, m, 64);
                pd += __shfl_xor(pd, m, 64);
            }
            if (fr == 0) {
                int row = bm + wm + mi * 16 + q * 4 + r;
                asrc[row * 4 + hd] = ps;
                adst[row * 4 + hd] = pd;
            }
        }
}

// ---------------- fused softmax + weighted fp16 gather + bias + ELU -> fp16 ----------------
// One wave per dst node; software-pipelined 16-edge chunks (R11/R13/R14).

__global__ __launch_bounds__(256) void agg_kernel(const _Float16* __restrict__ H16,
                                                  const float* __restrict__ asrc,
                                                  const float* __restrict__ adst,
                                                  const int* __restrict__ rowptr,
                                                  const int* __restrict__ csrsrc,
                                                  const float4* __restrict__ bias4,
                                                  half8* __restrict__ xo) {
    int wave = threadIdx.x >> 6, lane = threadIdx.x & 63;
    int n = blockIdx.x * 4 + wave;
    if (n >= NND) return;
    int rs = rowptr[n], re = rowptr[n + 1];
    int hd = lane >> 4;          // head for exp computation
    int sub = lane & 15;
    int l32 = lane & 31;         // output channel-group (8 ch)
    int myh = l32 >> 3;          // head of my output channels
    int epar = lane >> 5;        // edge parity this half handles
    float adv = adst[n * 4 + hd];
    float acc[8] = {};
    float ssum = 0.f;
    const _Float16* hb = H16 + l32 * 8;

    // prologue prefetch
    int sl = rs + sub;
    bool ok = sl < re;
    int idx = ok ? csrsrc[sl] : 0;
    float aval = asrc[idx * 4 + hd];

    for (int e0 = rs; e0 < re; e0 += 16) {
        float ev = 0.f;
        if (ok) {
            float a = aval + adv;
            a = a > 0.f ? a : NEG * a;
            ev = __expf(a);
        }
        ssum += ev;
        int idxv = idx;
        // prefetch next chunk (loads issue before the gather phase below)
        int sl2 = e0 + 16 + sub;
        bool ok2 = sl2 < re;
        int idx2 = ok2 ? csrsrc[sl2] : 0;
        float aval2 = asrc[idx2 * 4 + hd];
        int cnt = re - e0; if (cnt > 16) cnt = 16;
        #pragma unroll
        for (int j2 = 0; j2 < 8; j2++) {
            if (j2 * 2 >= cnt) break;
            int j = j2 * 2 + epar;
            int s = __shfl(idxv, j, 64);
            float ww = __shfl(ev, myh * 16 + j, 64);
            half8 hv = *(const half8*)&hb[(size_t)s * CCH];
            #pragma unroll
            for (int k = 0; k < 8; k++) acc[k] += ww * (float)hv[k];
        }
        idx = idx2; aval = aval2; ok = ok2;
    }
    // per-head softmax denominator: reduce over the 16 sub-lanes of each quarter
    for (int off = 1; off < 16; off <<= 1) ssum += __shfl_xor(ssum, off, 64);
    float inv = 1.f / __shfl(ssum, myh * 16, 64);
    // fold the two edge-parity halves
    #pragma unroll
    for (int k = 0; k < 8; k++) acc[k] += __shfl_xor(acc[k], 32, 64);
    if (lane < 32) {
        float4 b0 = bias4[l32 * 2], b1 = bias4[l32 * 2 + 1];
        float o[8];
        o[0] = acc[0] * inv + b0.x; o[1] = acc[1] * inv + b0.y;
        o[2] = acc[2] * inv + b0.z; o[3] = acc[3] * inv + b0.w;
        o[4] = acc[4] * inv + b1.x; o[5] = acc[5] * inv + b1.y;
        o[6] = acc[6] * inv + b1.z; o[7] = acc[7] * inv + b1.w;
        half8 h;
        #pragma unroll
        for (int k = 0; k < 8; k++) {
            float v = o[k];
            v = v > 0.f ? v : expm1f(v);
            h[k] = (_Float16)v;
        }
        xo[(size_t)n * 32 + l32] = h;
    }
}

// ---------------- pooling + final linear + L2 norm (fused) ----------------

__global__ __launch_bounds__(256) void poolfinal_kernel(const _Float16* __restrict__ xa,
                                                        const int* __restrict__ gstart,
                                                        const float* __restrict__ Wf,
                                                        const float* __restrict__ bfv,
                                                        float* __restrict__ out) {
    int g = blockIdx.x, t = threadIdx.x;
    __shared__ float gm[256];
    __shared__ float red[128];
    int s = gstart[g], e = gstart[g + 1];
    float acc = 0.f;
    for (int i = s; i < e; i++)
        acc += (float)xa[(size_t)i * CCH + t];
    int cnt = e - s;
    gm[t] = acc / (float)(cnt > 0 ? cnt : 1);
    __syncthreads();
    float a = 0.f;
    if (t < OUTD) {
        a = bfv[t];
        for (int k = 0; k < CCH; k++) a += gm[k] * Wf[k * OUTD + t];
        red[t] = a * a;
    }
    __syncthreads();
    for (int sft = 64; sft > 0; sft >>= 1) {
        if (t < sft) red[t] += red[t + sft];
        __syncthreads();
    }
    if (t < OUTD) out[g * OUTD + t] = a / fmaxf(sqrtf(red[0]), 1e-12f);
}

// ---------------- launch ----------------

extern "C" void kernel_launch(void* const* d_in, const int* in_sizes, int n_in,
                              void* d_out, int out_size, void* d_ws, size_t ws_size,
                              hipStream_t stream) {
    const float* x     = (const float*)d_in[0];
    const int*   ei    = (const int*)d_in[1];
    const int*   batch = (const int*)d_in[2];
    const float* W[3]  = {(const float*)d_in[3], (const float*)d_in[7],  (const float*)d_in[11]};
    const float* As[3] = {(const float*)d_in[4], (const float*)d_in[8],  (const float*)d_in[12]};
    const float* Ad[3] = {(const float*)d_in[5], (const float*)d_in[9],  (const float*)d_in[13]};
    const float* Bb[3] = {(const float*)d_in[6], (const float*)d_in[10], (const float*)d_in[14]};
    const float* Wf    = (const float*)d_in[15];
    const float* bf    = (const float*)d_in[16];
    float* out = (float*)d_out;

    // workspace layout
    _Float16* H16   = (_Float16*)d_ws;                            // M2*256 fp16 (gemm out / gather in)
    _Float16* act16 = H16 + (size_t)M2 * CCH;                     // M2*256 fp16 (agg out / gemm in)
    _Float16* wt0   = act16 + (size_t)M2 * CCH;                   // 256*128
    _Float16* wt1   = wt0 + 256 * 128;                            // 256*256
    _Float16* wt2   = wt1 + 256 * 256;                            // 256*256
    float* asrc  = (float*)(wt2 + 256 * 256);                     // M2*4
    float* adst  = asrc + (size_t)M2 * 4;                         // M2*4
    int* deg     = (int*)(adst + (size_t)M2 * 4);                 // NND+1
    int* rowptr  = deg + (NND + 1);
    int* cursor  = rowptr + (NND + 1);
    int* csrsrc  = cursor + (NND + 1);                            // ETOT
    int* gstart  = csrsrc + ETOT;                                 // NG+1
    int* bsum    = gstart + (NG + 1);                             // NBLK

    _Float16* wt[3] = {wt0, wt1, wt2};

    // fused prep (zero deg | bounds | x->fp16 | W->fp16^T), then CSR build
    prep_kernel<<<196 + 196 + XBLK + 640, 256, 0, stream>>>(
        batch, deg, gstart, (const float4*)x, (half4*)act16,
        W[0], W[1], W[2], wt0, wt1, wt2);
    count_kernel<<<(ETOT + 255) / 256, 256, 0, stream>>>(ei, deg);
    scan_part_kernel<<<NBLK, 256, 0, stream>>>(deg, bsum);
    scan_write_kernel<<<NBLK, 256, 0, stream>>>(deg, bsum, rowptr, cursor);
    scatter_kernel<<<(ETOT + 255) / 256, 256, 0, stream>>>(ei, cursor, csrsrc);

    // 3 GAT layers
    int K = FEAT;
    for (int l = 0; l < 3; l++) {
        dim3 g(2, M2 / 128);
        gemm_mfma_kernel<<<g, 256, 0, stream>>>(act16, wt[l], As[l], Ad[l], H16, asrc, adst, K);
        agg_kernel<<<(NND + 3) / 4, 256, 0, stream>>>(H16, asrc, adst, rowptr, csrsrc,
                                                      (const float4*)Bb[l], (half8*)act16);
        K = CCH;
    }

    // global mean pool + final linear + L2 normalize (fused)
    poolfinal_kernel<<<NG, 256, 0, stream>>>(act16, gstart, Wf, bf, out);
}